// Round 12
// baseline (150.032 us; speedup 1.0000x reference)
//
#include <hip/hip_runtime.h>

// GraphAttentionLayer: B=1, N=4096, F=256, H=8, U=64
//
// e_src cancels in softmax over j =>
//   out[i, u*8+h] = relu( (A @ (w*h))[i, h*64+u] / (A @ w)[i, h] ),  w = exp(e_dst)
// => ONE dense GEMM  C = A(4096x4096) x G(4096x544), G = [w*h (512) | w (8) | 0 (24)]
//
// R15: two-front attack based on R14's null (total stuck at 146; k_hg and
// k_out both hide below the 43us profiling cutoff; launch OH is small per R12
// arithmetic).
//  k_gemm: BK 256->512. Same per-iter ILP shape (4 indep B-loads + 4 A
//  ds_reads + 4 MFMA) but 8 barrier-free ds-iters per chunk (was 4) and 3
//  inner barrier pairs (was 7) -> the compiler's vmcnt(0)-at-barrier drain
//  amortizes 2x. LDS 2x32KB, 2 blk/CU preserved (no m132 occupancy cliff).
//  k_out: float4 loads/stores (was scalar) — if it was the hidden ~40us,
//  this collapses it; the outcome size disambiguates.
//  k_hg: frozen (R14 8-wave version).
//
// Gtp layout (HW-verified R4): tile (tk=k>>4, nt=n>>5), id=tk*17+nt, 1024 B:
//   u16[ id*512 + ((n&31) + 32*((k&15)>>3))*8 + (k&7) ]
// A/B MFMA frag (HW-verified R11): data[lane*8+i] = M[row=lane&31][k=(lane>>5)*8+i]
//
// ws: P 2 slabs (17,039,360 B) | Gtp @17039360 (4,456,448 B).

typedef unsigned short u16;
typedef unsigned int   u32;
typedef __attribute__((ext_vector_type(8)))  short  short8;    // 8 bf16 (4 VGPR)
typedef __attribute__((ext_vector_type(16))) float  floatx16;  // 32x32 MFMA acc
typedef __attribute__((ext_vector_type(8)))  unsigned short u16x8;
typedef __attribute__((ext_vector_type(4)))  unsigned short u16x4;

__device__ __forceinline__ u16 f2bf(float x) {
  u32 u = __float_as_uint(x);
  u += 0x7fffu + ((u >> 16) & 1u);   // RNE
  return (u16)(u >> 16);
}
__device__ __forceinline__ float bf2f(u16 h) {
  return __uint_as_float((u32)h << 16);
}
// split fp32[8] -> hi/lo bf16 short8 (hi RNE; lo = RNE(x - hi), rel err ~2^-17)
__device__ __forceinline__ void split8(const float* v, short8& hi, short8& lo) {
#pragma unroll
  for (int i = 0; i < 8; ++i) {
    u16 h = f2bf(v[i]);
    hi[i] = (short)h;
    lo[i] = (short)f2bf(v[i] - bf2f(h));
  }
}

// ---------------------------------------------------------------------------
// Kernel 1: h = X@W via split-bf16 3-pass MFMA, e_dst -> w = exp, write Gtp.
// (R14-frozen: 512 thr = 8 waves = 4 n-tiles x 2 K-halves; ks=1 partials via
// LDS; no LDS staging in K loop. Grid (128,4) = 512 blocks = 4 waves/SIMD.)
// ---------------------------------------------------------------------------
__global__ __launch_bounds__(512, 4) void k_hg(const float* __restrict__ X,
                                               const float* __restrict__ W,
                                               const float* __restrict__ av,
                                               u16* __restrict__ Gtp) {
  __shared__ float hbuf[4][64][17];   // partial-h exchange, pad 17 (17.4 KB)
  __shared__ float eL[64];            // [j_local*2 + head_local]
  __shared__ float w8L[64];
  const int t    = threadIdx.x;
  const int bx   = blockIdx.x;         // m-tile (32 j)
  const int y    = blockIdx.y;         // heads 2y, 2y+1
  const int j0   = bx * 32;
  const int wn   = t >> 6, lane = t & 63;
  const int ml   = lane & 31, kh = lane >> 5;
  const int wq   = wn & 3;             // n-tile slot
  const int ks   = wn >> 2;            // K-half
  const int ct   = y * 4 + wq;
  const int c    = ct * 32 + ml;       // global col (0..511)
  const int hl   = wq >> 1;            // head_local 0/1

  if (t < 64) eL[t] = 0.f;
  __syncthreads();

  floatx16 a0, a1;
#pragma unroll
  for (int r = 0; r < 16; ++r) { a0[r] = 0.f; a1[r] = 0.f; }

  const float* xrow = X + (size_t)(j0 + ml) * 256 + kh * 8;   // this lane's A row
  const float* wcol = W + (size_t)(kh * 8) * 512 + c;          // this lane's B col

#pragma unroll
  for (int kp = 0; kp < 4; ++kp) {     // kt = ks*8 + 2kp, +1
    const int kb0 = (ks * 8 + 2 * kp) * 16, kb1 = kb0 + 16;
    float xv0[8], xv1[8];
    {
      float4 u0 = *(const float4*)(xrow + kb0);
      float4 u1 = *(const float4*)(xrow + kb0 + 4);
      float4 u2 = *(const float4*)(xrow + kb1);
      float4 u3 = *(const float4*)(xrow + kb1 + 4);
      xv0[0]=u0.x; xv0[1]=u0.y; xv0[2]=u0.z; xv0[3]=u0.w;
      xv0[4]=u1.x; xv0[5]=u1.y; xv0[6]=u1.z; xv0[7]=u1.w;
      xv1[0]=u2.x; xv1[1]=u2.y; xv1[2]=u2.z; xv1[3]=u2.w;
      xv1[4]=u3.x; xv1[5]=u3.y; xv1[6]=u3.z; xv1[7]=u3.w;
    }
    float wv0[8], wv1[8];
#pragma unroll
    for (int i = 0; i < 8; ++i) {
      wv0[i] = wcol[(size_t)(kb0 + i) * 512];
      wv1[i] = wcol[(size_t)(kb1 + i) * 512];
    }
    short8 xh0, xl0, xh1, xl1, wh0, wl0, wh1, wl1;
    split8(xv0, xh0, xl0); split8(xv1, xh1, xl1);
    split8(wv0, wh0, wl0); split8(wv1, wh1, wl1);
    a0 = __builtin_amdgcn_mfma_f32_32x32x16_bf16(xh0, wh0, a0, 0, 0, 0);
    a1 = __builtin_amdgcn_mfma_f32_32x32x16_bf16(xh1, wh1, a1, 0, 0, 0);
    a0 = __builtin_amdgcn_mfma_f32_32x32x16_bf16(xh0, wl0, a0, 0, 0, 0);
    a1 = __builtin_amdgcn_mfma_f32_32x32x16_bf16(xh1, wl1, a1, 0, 0, 0);
    a0 = __builtin_amdgcn_mfma_f32_32x32x16_bf16(xl0, wh0, a0, 0, 0, 0);
    a1 = __builtin_amdgcn_mfma_f32_32x32x16_bf16(xl1, wh1, a1, 0, 0, 0);
  }
  floatx16 hacc;
#pragma unroll
  for (int r = 0; r < 16; ++r) hacc[r] = a0[r] + a1[r];

  // combine K-halves: ks=1 deposits, ks=0 adds
  if (ks == 1) {
#pragma unroll
    for (int r = 0; r < 16; ++r) hbuf[wq][lane][r] = hacc[r];
  }
  __syncthreads();
  if (ks == 0) {
#pragma unroll
    for (int r = 0; r < 16; ++r) hacc[r] += hbuf[wq][lane][r];

    const float ad = av[64 + (c & 63)];
    float p[16];
#pragma unroll
    for (int r = 0; r < 16; ++r) p[r] = hacc[r] * ad;
#pragma unroll
    for (int m = 1; m <= 16; m <<= 1)
#pragma unroll
      for (int r = 0; r < 16; ++r) p[r] += __shfl_xor(p[r], m);
    if (ml == 0) {
#pragma unroll
      for (int r = 0; r < 16; ++r) {
        int jl = (r & 3) + 8 * (r >> 2) + 4 * kh;
        atomicAdd(&eL[jl * 2 + hl], p[r]);
      }
    }
  }
  __syncthreads();
  if (t < 64) {
    float e = fminf(30.f, fmaxf(-30.f, eL[t]));
    w8L[t] = __expf(e);
  }
  __syncthreads();

  if (ks == 0) {
#pragma unroll
    for (int r = 0; r < 16; ++r) {
      int jl = (r & 3) + 8 * (r >> 2) + 4 * kh;
      int j  = j0 + jl;
      float g = hacc[r] * w8L[jl * 2 + hl];
      Gtp[(size_t)((j >> 4) * 17 + ct) * 512 + ((c & 31) + 32 * ((j & 15) >> 3)) * 8 + (j & 7)] =
          f2bf(g);
    }
  }
  if (t < 64) {
    int jj = t >> 1, lh2 = t & 1, h = 2 * y + lh2, j = j0 + jj;
    Gtp[(size_t)((j >> 4) * 17 + 16) * 512 + (h + 32 * ((jj & 15) >> 3)) * 8 + (jj & 7)] =
        f2bf(w8L[jj * 2 + lh2]);
  }
  if (y == 3 && t < 96) {
    int tk2 = t / 48, r = t - tk2 * 48;
    int slot = (r < 24) ? (8 + r) : (16 + r);
    u16x8 z = {0, 0, 0, 0, 0, 0, 0, 0};
    *(u16x8*)(Gtp + (size_t)(((j0 >> 4) + tk2) * 17 + 16) * 512 + slot * 8) = z;
  }
}

// ---------------------------------------------------------------------------
// Kernel 2: Pz = A(fp32,{0,1}) x G^T via 32x32x16 bf16 MFMA, PLAIN stores.
// R15: BK 256->512 (4 chunks, 8 barrier-free ds-iters/chunk, 3 inner barrier
// pairs). Per ds-iter shape unchanged (4 indep B-loads + 4 A ds_reads +
// 4 MFMA). BM=32, N-split, Z=2, XCD-pinned, launch_bounds(512,4).
// ---------------------------------------------------------------------------
__global__ __launch_bounds__(512, 4) void k_gemm(const float* __restrict__ A,
                                                 const u16* __restrict__ Gtp,
                                                 float* __restrict__ P) {
  __shared__ __align__(16) u16 As[2][32 * 512];  // 2 x 32 KB
  const int t    = threadIdx.x;
  const int bid  = blockIdx.x;
  const int xcd  = bid & 7, seq = bid >> 3;      // HW round-robins blockIdx%8 -> XCD
  const int z    = xcd >> 2;                     // k-slice, constant per XCD
  const int idx  = ((xcd & 3) << 6) + seq;       // 0..255 per z
  const int strip = idx >> 1;                    // 0..127
  const int nh   = idx & 1;                      // n-half
  const int i0   = strip * 32;
  const int kt0  = z * 2048;
  const int w    = t >> 6, lane = t & 63;
  const int ml   = lane & 31, kh = lane >> 5;
  const int nt   = nh * 8 + w;                   // this wave's n-tile

  floatx16 c0, dn;
#pragma unroll
  for (int r = 0; r < 16; ++r) { c0[r] = 0.f; dn[r] = 0.f; }

  // A staging: thread -> row ar (0..31), q-th float4 at k = (t&15)*4 + q*64,
  // q = 0..7 (512 floats/row/chunk). 16B-unit = (t&15)>>1 + q*8, 64 units/row.
  const int ar  = t >> 4;
  const int af  = (t & 15) * 4;
  const float* pa = A + (size_t)(i0 + ar) * 4096 + kt0 + af;
  const int sbase = ar * 512 + (t & 1) * 4;   // + swizzled unit*8
  const int scb   = (t & 15) >> 1;            // unit = q*8 + scb
  const int arx   = ar & 7;

  // A-frag reads: row m = ml, unit u -> physical u^(ml&7); k-tile j <-> unit 2j+kh
  const int arow = ml * 512;
  const int mx   = ml & 7;

  float4 areg[8];
#pragma unroll
  for (int q = 0; q < 8; ++q) areg[q] = *(const float4*)(pa + q * 64);
#pragma unroll
  for (int q = 0; q < 8; ++q) {
    u16x4 v = {f2bf(areg[q].x), f2bf(areg[q].y), f2bf(areg[q].z), f2bf(areg[q].w)};
    *(u16x4*)(&As[0][sbase + ((q * 8 + scb) ^ arx) * 8]) = v;
  }
  __syncthreads();

  for (int cc = 0; cc < 4; ++cc) {
    const int cb = cc & 1;
    if (cc < 3) {                    // prefetch next chunk early (hidden by compute)
#pragma unroll
      for (int q = 0; q < 8; ++q)
        areg[q] = *(const float4*)(pa + (cc + 1) * 512 + q * 64);
    }
    const int ktb = (kt0 >> 4) + cc * 32;
#pragma unroll 2
    for (int ds = 0; ds < 8; ++ds) {
      short8 b0 = *(const short8*)(Gtp + (size_t)((ktb + ds * 4 + 0) * 17 + nt) * 512 + lane * 8);
      short8 b1 = *(const short8*)(Gtp + (size_t)((ktb + ds * 4 + 1) * 17 + nt) * 512 + lane * 8);
      short8 b2 = *(const short8*)(Gtp + (size_t)((ktb + ds * 4 + 2) * 17 + nt) * 512 + lane * 8);
      short8 b3 = *(const short8*)(Gtp + (size_t)((ktb + ds * 4 + 3) * 17 + nt) * 512 + lane * 8);
      short8 a0 = *(const short8*)(&As[cb][arow + ((ds * 8 + 0 + kh) ^ mx) * 8]);
      short8 a1 = *(const short8*)(&As[cb][arow + ((ds * 8 + 2 + kh) ^ mx) * 8]);
      short8 a2 = *(const short8*)(&As[cb][arow + ((ds * 8 + 4 + kh) ^ mx) * 8]);
      short8 a3 = *(const short8*)(&As[cb][arow + ((ds * 8 + 6 + kh) ^ mx) * 8]);
      c0 = __builtin_amdgcn_mfma_f32_32x32x16_bf16(a0, b0, c0, 0, 0, 0);
      c0 = __builtin_amdgcn_mfma_f32_32x32x16_bf16(a1, b1, c0, 0, 0, 0);
      c0 = __builtin_amdgcn_mfma_f32_32x32x16_bf16(a2, b2, c0, 0, 0, 0);
      c0 = __builtin_amdgcn_mfma_f32_32x32x16_bf16(a3, b3, c0, 0, 0, 0);
    }
    // den tile 16: wave covers k-tiles {4w..4w+3} of this chunk (nh==0 only)
    if (nh == 0) {
#pragma unroll
      for (int q = 0; q < 4; ++q) {
        short8 e = *(const short8*)(Gtp + (size_t)((ktb + w * 4 + q) * 17 + 16) * 512 + lane * 8);
        short8 a = *(const short8*)(&As[cb][arow + ((w * 8 + 2 * q + kh) ^ mx) * 8]);
        dn = __builtin_amdgcn_mfma_f32_32x32x16_bf16(a, e, dn, 0, 0, 0);
      }
    }
    if (cc < 3) {
      __syncthreads();               // readers of other buffer done
#pragma unroll
      for (int q = 0; q < 8; ++q) {
        u16x4 v = {f2bf(areg[q].x), f2bf(areg[q].y), f2bf(areg[q].z), f2bf(areg[q].w)};
        *(u16x4*)(&As[cb ^ 1][sbase + ((q * 8 + scb) ^ arx) * 8]) = v;
      }
      __syncthreads();               // writes visible
    }
  }

  // ---- epilogue: plain stores to slab z (no atomics) ----
  float* Pz = P + (size_t)z * (4096 * 520);
  const int col0 = nt * 32 + ml;
  // C/D layout: col = lane&31, row = (r&3) + 8*(r>>2) + 4*(lane>>5)
#pragma unroll
  for (int r = 0; r < 16; ++r) {
    int row = i0 + 4 * kh + (r & 3) + 8 * (r >> 2);
    Pz[(size_t)row * 520 + col0] = c0[r];
  }

  // den cols 512..519: reduce dn across the 8 waves via LDS (As[0] free:
  // last read in chunk cc==2; all waves past that barrier pair are in cc==3
  // which reads As[1] only).
  if (nh == 0) {
    float* dred = (float*)&As[0][0];   // 8 waves x 32 rows x 8 cols = 8 KB
    if (ml < 8) {
#pragma unroll
      for (int r = 0; r < 16; ++r) {
        int row32 = 4 * kh + (r & 3) + 8 * (r >> 2);
        dred[(w * 32 + row32) * 8 + ml] = dn[r];
      }
    }
    __syncthreads();
    if (t < 256) {
      int row = t >> 3, c = t & 7;   // 32 rows x 8 cols
      float s = 0.f;
#pragma unroll
      for (int ww = 0; ww < 8; ++ww) s += dred[(ww * 32 + row) * 8 + c];
      Pz[(size_t)(i0 + row) * 520 + 512 + c] = s;
    }
  }
}

// ---------------------------------------------------------------------------
// Kernel 3: out[i, u*8+h] = relu( SUMz Pz[i][h*64+u] / SUMz Pz[i][512+h] ).
// R15: float4 loads/stores. 2 rows/block, 2048 blocks.
// ---------------------------------------------------------------------------
__global__ __launch_bounds__(256) void k_out(const float* __restrict__ P,
                                             float* __restrict__ out) {
  __shared__ float ps[2][520];
  const size_t SL = (size_t)4096 * 520;
  const int t    = threadIdx.x;
  const int half = t >> 7, lt = t & 127;
  const int i    = blockIdx.x * 2 + half;
  const float* pr = P + (size_t)i * 520;
  {
    float4 v0 = *(const float4*)(pr + lt * 4);
    float4 v1 = *(const float4*)(pr + SL + lt * 4);
    float4 s  = {v0.x + v1.x, v0.y + v1.y, v0.z + v1.z, v0.w + v1.w};
    *(float4*)(&ps[half][lt * 4]) = s;
    if (lt < 8) ps[half][512 + lt] = pr[512 + lt] + pr[SL + 512 + lt];
  }
  __syncthreads();
  {
    float ov[4];
#pragma unroll
    for (int q = 0; q < 4; ++q) {
      int c = lt * 4 + q;             // c = u*8 + hd
      int u = c >> 3, hd = c & 7;
      float o = ps[half][hd * 64 + u] / ps[half][512 + hd];
      ov[q] = fmaxf(o, 0.f);
    }
    *(float4*)(out + (size_t)i * 512 + lt * 4) = *(float4*)ov;
  }
}

extern "C" void kernel_launch(void* const* d_in, const int* in_sizes, int n_in,
                              void* d_out, int out_size, void* d_ws, size_t ws_size,
                              hipStream_t stream) {
  const float* X  = (const float*)d_in[0];
  const float* A  = (const float*)d_in[1];
  const float* W  = (const float*)d_in[2];
  const float* av = (const float*)d_in[3];
  float* out = (float*)d_out;
  char*  ws  = (char*)d_ws;

  float* P   = (float*)ws;                  // 2 slabs x 4096 x 520 fp32
  u16*   Gtp = (u16*)(ws + 17039360);       // 256*17 tiles * 1024 B

  k_hg<<<dim3(128, 4), 512, 0, stream>>>(X, W, av, Gtp);
  k_gemm<<<512, 512, 0, stream>>>(A, Gtp, P);
  k_out<<<2048, 256, 0, stream>>>(P, out);
}

// Round 13
// 144.262 us; speedup vs baseline: 1.0400x; 1.0400x over previous
//
#include <hip/hip_runtime.h>

// GraphAttentionLayer: B=1, N=4096, F=256, H=8, U=64
//
// e_src cancels in softmax over j =>
//   out[i, u*8+h] = relu( (A @ (w*h))[i, h*64+u] / (A @ w)[i, h] ),  w = exp(e_dst)
// => ONE dense GEMM  C = A(4096x4096) x G(4096x544), G = [w*h (512) | w (8) | 0 (24)]
//
// R16: B-load ILP deepening. R15 regressed (BK=512: 46.8us, FETCH/WRITE up ->
// revert to BK=256) and k_out-float4 was null (k_out was already small).
// Budget: k_gemm 44 (3x its ~15us L2 floor), k_hg ~40 (hidden), k_out ~8.
//  k_gemm: BK=256, inner loop 2 ds-iters x {8 indep B-loads + 8 A ds_reads
//  + 8 MFMA} (was 4x{4+4+4}) -> double outstanding B misses per wave.
//  VGPR ~121 < 128 cap, no spill. Everything else R14-frozen.
//  k_hg: R14-frozen. k_out: R15 float4.
//
// Gtp layout (HW-verified R4): tile (tk=k>>4, nt=n>>5), id=tk*17+nt, 1024 B:
//   u16[ id*512 + ((n&31) + 32*((k&15)>>3))*8 + (k&7) ]
// A/B MFMA frag (HW-verified R11): data[lane*8+i] = M[row=lane&31][k=(lane>>5)*8+i]
//
// ws: P 2 slabs (17,039,360 B) | Gtp @17039360 (4,456,448 B).

typedef unsigned short u16;
typedef unsigned int   u32;
typedef __attribute__((ext_vector_type(8)))  short  short8;    // 8 bf16 (4 VGPR)
typedef __attribute__((ext_vector_type(16))) float  floatx16;  // 32x32 MFMA acc
typedef __attribute__((ext_vector_type(8)))  unsigned short u16x8;
typedef __attribute__((ext_vector_type(4)))  unsigned short u16x4;

__device__ __forceinline__ u16 f2bf(float x) {
  u32 u = __float_as_uint(x);
  u += 0x7fffu + ((u >> 16) & 1u);   // RNE
  return (u16)(u >> 16);
}
__device__ __forceinline__ float bf2f(u16 h) {
  return __uint_as_float((u32)h << 16);
}
// split fp32[8] -> hi/lo bf16 short8 (hi RNE; lo = RNE(x - hi), rel err ~2^-17)
__device__ __forceinline__ void split8(const float* v, short8& hi, short8& lo) {
#pragma unroll
  for (int i = 0; i < 8; ++i) {
    u16 h = f2bf(v[i]);
    hi[i] = (short)h;
    lo[i] = (short)f2bf(v[i] - bf2f(h));
  }
}

// ---------------------------------------------------------------------------
// Kernel 1: h = X@W via split-bf16 3-pass MFMA, e_dst -> w = exp, write Gtp.
// (R14-frozen: 512 thr = 8 waves = 4 n-tiles x 2 K-halves; ks=1 partials via
// LDS; no LDS staging in K loop. Grid (128,4) = 512 blocks = 4 waves/SIMD.)
// ---------------------------------------------------------------------------
__global__ __launch_bounds__(512, 4) void k_hg(const float* __restrict__ X,
                                               const float* __restrict__ W,
                                               const float* __restrict__ av,
                                               u16* __restrict__ Gtp) {
  __shared__ float hbuf[4][64][17];   // partial-h exchange, pad 17 (17.4 KB)
  __shared__ float eL[64];            // [j_local*2 + head_local]
  __shared__ float w8L[64];
  const int t    = threadIdx.x;
  const int bx   = blockIdx.x;         // m-tile (32 j)
  const int y    = blockIdx.y;         // heads 2y, 2y+1
  const int j0   = bx * 32;
  const int wn   = t >> 6, lane = t & 63;
  const int ml   = lane & 31, kh = lane >> 5;
  const int wq   = wn & 3;             // n-tile slot
  const int ks   = wn >> 2;            // K-half
  const int ct   = y * 4 + wq;
  const int c    = ct * 32 + ml;       // global col (0..511)
  const int hl   = wq >> 1;            // head_local 0/1

  if (t < 64) eL[t] = 0.f;
  __syncthreads();

  floatx16 a0, a1;
#pragma unroll
  for (int r = 0; r < 16; ++r) { a0[r] = 0.f; a1[r] = 0.f; }

  const float* xrow = X + (size_t)(j0 + ml) * 256 + kh * 8;   // this lane's A row
  const float* wcol = W + (size_t)(kh * 8) * 512 + c;          // this lane's B col

#pragma unroll
  for (int kp = 0; kp < 4; ++kp) {     // kt = ks*8 + 2kp, +1
    const int kb0 = (ks * 8 + 2 * kp) * 16, kb1 = kb0 + 16;
    float xv0[8], xv1[8];
    {
      float4 u0 = *(const float4*)(xrow + kb0);
      float4 u1 = *(const float4*)(xrow + kb0 + 4);
      float4 u2 = *(const float4*)(xrow + kb1);
      float4 u3 = *(const float4*)(xrow + kb1 + 4);
      xv0[0]=u0.x; xv0[1]=u0.y; xv0[2]=u0.z; xv0[3]=u0.w;
      xv0[4]=u1.x; xv0[5]=u1.y; xv0[6]=u1.z; xv0[7]=u1.w;
      xv1[0]=u2.x; xv1[1]=u2.y; xv1[2]=u2.z; xv1[3]=u2.w;
      xv1[4]=u3.x; xv1[5]=u3.y; xv1[6]=u3.z; xv1[7]=u3.w;
    }
    float wv0[8], wv1[8];
#pragma unroll
    for (int i = 0; i < 8; ++i) {
      wv0[i] = wcol[(size_t)(kb0 + i) * 512];
      wv1[i] = wcol[(size_t)(kb1 + i) * 512];
    }
    short8 xh0, xl0, xh1, xl1, wh0, wl0, wh1, wl1;
    split8(xv0, xh0, xl0); split8(xv1, xh1, xl1);
    split8(wv0, wh0, wl0); split8(wv1, wh1, wl1);
    a0 = __builtin_amdgcn_mfma_f32_32x32x16_bf16(xh0, wh0, a0, 0, 0, 0);
    a1 = __builtin_amdgcn_mfma_f32_32x32x16_bf16(xh1, wh1, a1, 0, 0, 0);
    a0 = __builtin_amdgcn_mfma_f32_32x32x16_bf16(xh0, wl0, a0, 0, 0, 0);
    a1 = __builtin_amdgcn_mfma_f32_32x32x16_bf16(xh1, wl1, a1, 0, 0, 0);
    a0 = __builtin_amdgcn_mfma_f32_32x32x16_bf16(xl0, wh0, a0, 0, 0, 0);
    a1 = __builtin_amdgcn_mfma_f32_32x32x16_bf16(xl1, wh1, a1, 0, 0, 0);
  }
  floatx16 hacc;
#pragma unroll
  for (int r = 0; r < 16; ++r) hacc[r] = a0[r] + a1[r];

  // combine K-halves: ks=1 deposits, ks=0 adds
  if (ks == 1) {
#pragma unroll
    for (int r = 0; r < 16; ++r) hbuf[wq][lane][r] = hacc[r];
  }
  __syncthreads();
  if (ks == 0) {
#pragma unroll
    for (int r = 0; r < 16; ++r) hacc[r] += hbuf[wq][lane][r];

    const float ad = av[64 + (c & 63)];
    float p[16];
#pragma unroll
    for (int r = 0; r < 16; ++r) p[r] = hacc[r] * ad;
#pragma unroll
    for (int m = 1; m <= 16; m <<= 1)
#pragma unroll
      for (int r = 0; r < 16; ++r) p[r] += __shfl_xor(p[r], m);
    if (ml == 0) {
#pragma unroll
      for (int r = 0; r < 16; ++r) {
        int jl = (r & 3) + 8 * (r >> 2) + 4 * kh;
        atomicAdd(&eL[jl * 2 + hl], p[r]);
      }
    }
  }
  __syncthreads();
  if (t < 64) {
    float e = fminf(30.f, fmaxf(-30.f, eL[t]));
    w8L[t] = __expf(e);
  }
  __syncthreads();

  if (ks == 0) {
#pragma unroll
    for (int r = 0; r < 16; ++r) {
      int jl = (r & 3) + 8 * (r >> 2) + 4 * kh;
      int j  = j0 + jl;
      float g = hacc[r] * w8L[jl * 2 + hl];
      Gtp[(size_t)((j >> 4) * 17 + ct) * 512 + ((c & 31) + 32 * ((j & 15) >> 3)) * 8 + (j & 7)] =
          f2bf(g);
    }
  }
  if (t < 64) {
    int jj = t >> 1, lh2 = t & 1, h = 2 * y + lh2, j = j0 + jj;
    Gtp[(size_t)((j >> 4) * 17 + 16) * 512 + (h + 32 * ((jj & 15) >> 3)) * 8 + (jj & 7)] =
        f2bf(w8L[jj * 2 + lh2]);
  }
  if (y == 3 && t < 96) {
    int tk2 = t / 48, r = t - tk2 * 48;
    int slot = (r < 24) ? (8 + r) : (16 + r);
    u16x8 z = {0, 0, 0, 0, 0, 0, 0, 0};
    *(u16x8*)(Gtp + (size_t)(((j0 >> 4) + tk2) * 17 + 16) * 512 + slot * 8) = z;
  }
}

// ---------------------------------------------------------------------------
// Kernel 2: Pz = A(fp32,{0,1}) x G^T via 32x32x16 bf16 MFMA, PLAIN stores.
// R16: BK=256 (reverted), inner loop 2 ds-iters x {8 indep B-loads + 8 A
// ds_reads + 8 MFMA} -> 2x outstanding B misses/wave vs R14. BM=32, N-split,
// Z=2, XCD-pinned, launch_bounds(512,4), 7 inner barrier pairs.
// ---------------------------------------------------------------------------
__global__ __launch_bounds__(512, 4) void k_gemm(const float* __restrict__ A,
                                                 const u16* __restrict__ Gtp,
                                                 float* __restrict__ P) {
  __shared__ __align__(16) u16 As[2][32 * 256];  // 2 x 16 KB
  const int t    = threadIdx.x;
  const int bid  = blockIdx.x;
  const int xcd  = bid & 7, seq = bid >> 3;      // HW round-robins blockIdx%8 -> XCD
  const int z    = xcd >> 2;                     // k-slice, constant per XCD
  const int idx  = ((xcd & 3) << 6) + seq;       // 0..255 per z
  const int strip = idx >> 1;                    // 0..127
  const int nh   = idx & 1;                      // n-half
  const int i0   = strip * 32;
  const int kt0  = z * 2048;
  const int w    = t >> 6, lane = t & 63;
  const int ml   = lane & 31, kh = lane >> 5;
  const int nt   = nh * 8 + w;                   // this wave's n-tile

  floatx16 c0, dn;
#pragma unroll
  for (int r = 0; r < 16; ++r) { c0[r] = 0.f; dn[r] = 0.f; }

  // A staging: thread -> row ar (0..31), q-th float4 at k = (t&15)*4 + q*64
  const int ar  = t >> 4;
  const int af  = (t & 15) * 4;
  const float* pa = A + (size_t)(i0 + ar) * 4096 + kt0 + af;
  const int sbase = ar * 256 + (t & 1) * 4;   // + swizzled granule*8
  const int scb   = (t & 15) >> 1;            // granule = q*8 + scb
  const int arx   = ar & 7;

  // A-frag reads: row m = ml, granule g -> physical g^(ml&7); k-tile j <-> granule 2j+kh
  const int arow = ml * 256;
  const int mx   = ml & 7;

  float4 areg[4];
#pragma unroll
  for (int q = 0; q < 4; ++q) areg[q] = *(const float4*)(pa + q * 64);
#pragma unroll
  for (int q = 0; q < 4; ++q) {
    u16x4 v = {f2bf(areg[q].x), f2bf(areg[q].y), f2bf(areg[q].z), f2bf(areg[q].w)};
    *(u16x4*)(&As[0][sbase + ((q * 8 + scb) ^ arx) * 8]) = v;
  }
  __syncthreads();

  for (int cc = 0; cc < 8; ++cc) {
    const int cb = cc & 1;
    if (cc < 7) {                    // prefetch next chunk early (hidden by compute)
#pragma unroll
      for (int q = 0; q < 4; ++q)
        areg[q] = *(const float4*)(pa + (cc + 1) * 256 + q * 64);
    }
    const int ktb = (kt0 >> 4) + cc * 16;
#pragma unroll
    for (int ds = 0; ds < 2; ++ds) {
      // 8 independent B-loads (k-tiles ds*8 .. ds*8+7 of this chunk)
      short8 b0 = *(const short8*)(Gtp + (size_t)((ktb + ds * 8 + 0) * 17 + nt) * 512 + lane * 8);
      short8 b1 = *(const short8*)(Gtp + (size_t)((ktb + ds * 8 + 1) * 17 + nt) * 512 + lane * 8);
      short8 b2 = *(const short8*)(Gtp + (size_t)((ktb + ds * 8 + 2) * 17 + nt) * 512 + lane * 8);
      short8 b3 = *(const short8*)(Gtp + (size_t)((ktb + ds * 8 + 3) * 17 + nt) * 512 + lane * 8);
      short8 b4 = *(const short8*)(Gtp + (size_t)((ktb + ds * 8 + 4) * 17 + nt) * 512 + lane * 8);
      short8 b5 = *(const short8*)(Gtp + (size_t)((ktb + ds * 8 + 5) * 17 + nt) * 512 + lane * 8);
      short8 b6 = *(const short8*)(Gtp + (size_t)((ktb + ds * 8 + 6) * 17 + nt) * 512 + lane * 8);
      short8 b7 = *(const short8*)(Gtp + (size_t)((ktb + ds * 8 + 7) * 17 + nt) * 512 + lane * 8);
      // matching A fragments from LDS (granule (2j+kh)^mx)
      short8 a0 = *(const short8*)(&As[cb][arow + ((ds * 16 +  0 + kh) ^ mx) * 8]);
      short8 a1 = *(const short8*)(&As[cb][arow + ((ds * 16 +  2 + kh) ^ mx) * 8]);
      short8 a2 = *(const short8*)(&As[cb][arow + ((ds * 16 +  4 + kh) ^ mx) * 8]);
      short8 a3 = *(const short8*)(&As[cb][arow + ((ds * 16 +  6 + kh) ^ mx) * 8]);
      short8 a4 = *(const short8*)(&As[cb][arow + ((ds * 16 +  8 + kh) ^ mx) * 8]);
      short8 a5 = *(const short8*)(&As[cb][arow + ((ds * 16 + 10 + kh) ^ mx) * 8]);
      short8 a6 = *(const short8*)(&As[cb][arow + ((ds * 16 + 12 + kh) ^ mx) * 8]);
      short8 a7 = *(const short8*)(&As[cb][arow + ((ds * 16 + 14 + kh) ^ mx) * 8]);
      c0 = __builtin_amdgcn_mfma_f32_32x32x16_bf16(a0, b0, c0, 0, 0, 0);
      c0 = __builtin_amdgcn_mfma_f32_32x32x16_bf16(a1, b1, c0, 0, 0, 0);
      c0 = __builtin_amdgcn_mfma_f32_32x32x16_bf16(a2, b2, c0, 0, 0, 0);
      c0 = __builtin_amdgcn_mfma_f32_32x32x16_bf16(a3, b3, c0, 0, 0, 0);
      c0 = __builtin_amdgcn_mfma_f32_32x32x16_bf16(a4, b4, c0, 0, 0, 0);
      c0 = __builtin_amdgcn_mfma_f32_32x32x16_bf16(a5, b5, c0, 0, 0, 0);
      c0 = __builtin_amdgcn_mfma_f32_32x32x16_bf16(a6, b6, c0, 0, 0, 0);
      c0 = __builtin_amdgcn_mfma_f32_32x32x16_bf16(a7, b7, c0, 0, 0, 0);
    }
    // den tile 16: wave covers k-tiles {2w, 2w+1} of this chunk (nh==0 only)
    if (nh == 0) {
      short8 e0 = *(const short8*)(Gtp + (size_t)((ktb + w * 2) * 17 + 16) * 512 + lane * 8);
      short8 e1 = *(const short8*)(Gtp + (size_t)((ktb + w * 2 + 1) * 17 + 16) * 512 + lane * 8);
      short8 a0 = *(const short8*)(&As[cb][arow + ((w * 4 + kh) ^ mx) * 8]);
      short8 a1 = *(const short8*)(&As[cb][arow + ((w * 4 + 2 + kh) ^ mx) * 8]);
      dn = __builtin_amdgcn_mfma_f32_32x32x16_bf16(a0, e0, dn, 0, 0, 0);
      dn = __builtin_amdgcn_mfma_f32_32x32x16_bf16(a1, e1, dn, 0, 0, 0);
    }
    if (cc < 7) {
      __syncthreads();               // readers of other buffer done
#pragma unroll
      for (int q = 0; q < 4; ++q) {
        u16x4 v = {f2bf(areg[q].x), f2bf(areg[q].y), f2bf(areg[q].z), f2bf(areg[q].w)};
        *(u16x4*)(&As[cb ^ 1][sbase + ((q * 8 + scb) ^ arx) * 8]) = v;
      }
      __syncthreads();               // writes visible
    }
  }

  // ---- epilogue: plain stores to slab z (no atomics) ----
  float* Pz = P + (size_t)z * (4096 * 520);
  const int col0 = nt * 32 + ml;
  // C/D layout: col = lane&31, row = (r&3) + 8*(r>>2) + 4*(lane>>5)
#pragma unroll
  for (int r = 0; r < 16; ++r) {
    int row = i0 + 4 * kh + (r & 3) + 8 * (r >> 2);
    Pz[(size_t)row * 520 + col0] = c0[r];
  }

  // den cols 512..519: reduce dn across the 8 waves via LDS (As[0] free:
  // last read in chunk cc==6, all waves past that barrier).
  if (nh == 0) {
    float* dred = (float*)&As[0][0];   // 8 waves x 32 rows x 8 cols = 8 KB
    if (ml < 8) {
#pragma unroll
      for (int r = 0; r < 16; ++r) {
        int row32 = 4 * kh + (r & 3) + 8 * (r >> 2);
        dred[(w * 32 + row32) * 8 + ml] = dn[r];
      }
    }
    __syncthreads();
    if (t < 256) {
      int row = t >> 3, c = t & 7;   // 32 rows x 8 cols
      float s = 0.f;
#pragma unroll
      for (int ww = 0; ww < 8; ++ww) s += dred[(ww * 32 + row) * 8 + c];
      Pz[(size_t)(i0 + row) * 520 + 512 + c] = s;
    }
  }
}

// ---------------------------------------------------------------------------
// Kernel 3: out[i, u*8+h] = relu( SUMz Pz[i][h*64+u] / SUMz Pz[i][512+h] ).
// float4 loads/stores. 2 rows/block, 2048 blocks.
// ---------------------------------------------------------------------------
__global__ __launch_bounds__(256) void k_out(const float* __restrict__ P,
                                             float* __restrict__ out) {
  __shared__ float ps[2][520];
  const size_t SL = (size_t)4096 * 520;
  const int t    = threadIdx.x;
  const int half = t >> 7, lt = t & 127;
  const int i    = blockIdx.x * 2 + half;
  const float* pr = P + (size_t)i * 520;
  {
    float4 v0 = *(const float4*)(pr + lt * 4);
    float4 v1 = *(const float4*)(pr + SL + lt * 4);
    float4 s  = {v0.x + v1.x, v0.y + v1.y, v0.z + v1.z, v0.w + v1.w};
    *(float4*)(&ps[half][lt * 4]) = s;
    if (lt < 8) ps[half][512 + lt] = pr[512 + lt] + pr[SL + 512 + lt];
  }
  __syncthreads();
  {
    float ov[4];
#pragma unroll
    for (int q = 0; q < 4; ++q) {
      int c = lt * 4 + q;             // c = u*8 + hd
      int u = c >> 3, hd = c & 7;
      float o = ps[half][hd * 64 + u] / ps[half][512 + hd];
      ov[q] = fmaxf(o, 0.f);
    }
    *(float4*)(out + (size_t)i * 512 + lt * 4) = *(float4*)ov;
  }
}

extern "C" void kernel_launch(void* const* d_in, const int* in_sizes, int n_in,
                              void* d_out, int out_size, void* d_ws, size_t ws_size,
                              hipStream_t stream) {
  const float* X  = (const float*)d_in[0];
  const float* A  = (const float*)d_in[1];
  const float* W  = (const float*)d_in[2];
  const float* av = (const float*)d_in[3];
  float* out = (float*)d_out;
  char*  ws  = (char*)d_ws;

  float* P   = (float*)ws;                  // 2 slabs x 4096 x 520 fp32
  u16*   Gtp = (u16*)(ws + 17039360);       // 256*17 tiles * 1024 B

  k_hg<<<dim3(128, 4), 512, 0, stream>>>(X, W, av, Gtp);
  k_gemm<<<512, 512, 0, stream>>>(A, Gtp, P);
  k_out<<<2048, 256, 0, stream>>>(P, out);
}